// Round 8
// baseline (241.196 us; speedup 1.0000x reference)
//
#include <hip/hip_runtime.h>
#include <stdint.h>

typedef unsigned long long u64;
typedef unsigned int u32;
typedef unsigned short u16;

#define NB 8
#define NN 2048
#define NC 80
#define ROW 84
#define OUT_K 200
#define IOU_T 0.5f
#define SCORE_T 0.01f
#define NG 10   // class-groups of 8 per batch

// ---- compare-exchange, descending network, direction from global index ----
__device__ __forceinline__ void ce_desc(u64* a, int i, int j, int k) {
    u64 a0 = a[i], a1 = a[i + j];
    bool up = ((i & k) == 0);
    if (up ? (a0 < a1) : (a0 > a1)) { a[i] = a1; a[i + j] = a0; }
}

// wave-local rounds on a 512-elem segment (4 CE/lane/round), j<=256
__device__ __forceinline__ void wave_rounds512(u64* a, int base, int k, int jhi, int lane) {
    for (int j = jhi; j > 0; j >>= 1) {
        #pragma unroll
        for (int p = 0; p < 4; p++) {
            int r = lane + p * 64;
            int low = r & (j - 1);
            int high = (r & ~(j - 1)) << 1;
            ce_desc(a, base + (high | low), j, k);
        }
        __builtin_amdgcn_wave_barrier();
    }
}

// wave-local rounds on a 256-elem segment; k=0x40000000 -> all-descending merge
__device__ __forceinline__ void wave_rounds256(u64* a, int base, int k, int jhi, int lane) {
    for (int j = jhi; j > 0; j >>= 1) {
        #pragma unroll
        for (int p = 0; p < 2; p++) {
            int r = lane + p * 64;
            int low = r & (j - 1);
            int high = (r & ~(j - 1)) << 1;
            ce_desc(a, base + (high | low), j, k);
        }
        __builtin_amdgcn_wave_barrier();
    }
}

// max-combine two desc-sorted 256-runs (base, base+off) -> top-256 sorted desc
__device__ __forceinline__ void pair_merge256(u64* a, int base, int off, int lane) {
    #pragma unroll
    for (int p0 = 0; p0 < 4; p0++) {
        int p = lane + p0 * 64;
        u64 xv = a[base + p];
        u64 yv = a[base + off + 255 - p];
        a[base + p] = xv > yv ? xv : yv;
    }
    __builtin_amdgcn_wave_barrier();
    wave_rounds256(a, base, 0x40000000, 128, lane);
}

// full hybrid bitonic sort of 2048 (desc) — identical network to rounds 4-7
__device__ __forceinline__ void sort2048(u64* key, int tid, int lane, int wv) {
    const int base = wv * 512;
    for (int k = 2; k <= 512; k <<= 1)
        wave_rounds512(key, base, k, k >> 1, lane);
    __syncthreads();
    #pragma unroll
    for (int p = 0; p < 4; p++) {                       // k=1024, j=512
        int r = tid + p * 256;
        int low = r & 511, high = (r & ~511) << 1;
        ce_desc(key, high | low, 512, 1024);
    }
    __syncthreads();
    wave_rounds512(key, base, 1024, 256, lane);
    __syncthreads();
    #pragma unroll
    for (int p = 0; p < 4; p++) {                       // k=2048, j=1024
        int r = tid + p * 256;
        int low = r & 1023, high = (r & ~1023) << 1;
        ce_desc(key, high | low, 1024, 2048);
    }
    __syncthreads();
    #pragma unroll
    for (int p = 0; p < 4; p++) {                       // k=2048, j=512
        int r = tid + p * 256;
        int low = r & 511, high = (r & ~511) << 1;
        ce_desc(key, high | low, 512, 2048);
    }
    __syncthreads();
    wave_rounds512(key, base, 2048, 256, lane);
    __syncthreads();
}

// exact reference-order IoU > 0.5 test (byte-identical to passing rounds 3-7)
__device__ __forceinline__ bool iou_gt_half(float4 a, float aa, float4 b, float ab) {
    float ltx = fmaxf(a.x, b.x);
    float lty = fmaxf(a.y, b.y);
    float rbx = fminf(a.z, b.z);
    float rby = fminf(a.w, b.w);
    float wd = fmaxf(__fsub_rn(rbx, ltx), 0.0f);
    float hd = fmaxf(__fsub_rn(rby, lty), 0.0f);
    float inter = __fmul_rn(wd, hd);
    float uni = __fsub_rn(__fadd_rn(aa, ab), inter);
    float m = fmaxf(uni, 1e-8f);
    float d2 = __fmul_rn(2.0f, inter);     // exact scaling
    bool sup = d2 > m;                      // == (inter/m > 0.5) exactly
    if (sup && (__fsub_rn(d2, m) <= __fmul_rn(m, 1.2e-7f)))
        sup = __fdiv_rn(inter, m) > IOU_T;  // fdiv boundary guard, ~never taken
    return sup;
}

// recompute kept-box area in VALU (bit-identical to the stored formula)
__device__ __forceinline__ bool iou_sup(float4 a, float aa, float4 b) {
    float ab = __fmul_rn(__fsub_rn(b.z, b.x), __fsub_rn(b.w, b.y));
    return iou_gt_half(a, aa, b, ab);
}

// test candidate vs kept[t0..t1) step `step`, x4 batched LDS broadcast reads
__device__ __forceinline__ bool kept_test(const float4* kb, int t0, int t1,
                                          int step, float4 bx, float ar) {
    bool sup = false;
    int t = t0;
    const int s1 = step, s2 = 2 * step, s3 = 3 * step, s4 = 4 * step;
    for (; t + s3 < t1; t += s4) {
        float4 k0 = kb[t], k1 = kb[t + s1], k2 = kb[t + s2], k3 = kb[t + s3];
        bool a0 = iou_sup(bx, ar, k0);
        bool a1 = iou_sup(bx, ar, k1);
        bool a2 = iou_sup(bx, ar, k2);
        bool a3 = iou_sup(bx, ar, k3);
        sup = sup | ((a0 | a1) | (a2 | a3));
    }
    for (; t < t1; t += step) sup = sup | iou_sup(bx, ar, kb[t]);
    return sup;
}

__device__ __forceinline__ float bcast(float v, int sl) {
    return __int_as_float(__builtin_amdgcn_readlane(__float_as_int(v), sl));
}

// ---- single fused kernel: sort + staged boxes + PIPELINED greedy + topk ----
__global__ __launch_bounds__(256) void nms_fused(
        const float* __restrict__ x, u64* __restrict__ cand_key,
        u64* __restrict__ ws2, int* __restrict__ cnt_g, int* __restrict__ cnt_b,
        float* __restrict__ out) {
    const int bc = blockIdx.x;
    const int b = bc / NC;
    const int c = bc % NC;
    const int tid = threadIdx.x;
    const int lane = tid & 63;
    const int wv = tid >> 6;

    // carved LDS: key 16K | sbox 32K (aliased by tail-merge buf) | kept 3.6K
    __shared__ __align__(16) unsigned char smem[16384 + 32768 + 3200 + 416];
    u64* key = (u64*)smem;                          // [2048]
    float4* sbox = (float4*)(smem + 16384);         // [2048] sorted boxes
    float4* kept_box = (float4*)(smem + 49152);     // [200]
    u16* kept_slot = (u16*)(smem + 52352);          // [200] sorted-pos of kept
    u64* buf = (u64*)(smem + 16384);                // [4096] tail merges (alias)
    __shared__ u64 s_sup[4];
    __shared__ int s_kept, s_done, s_role;

    const float* xb = x + (size_t)b * NN * ROW;

    // build keys (score desc, index asc; low 11 bits = 2047-orig)
    #pragma unroll
    for (int w = 0; w < 8; w++) {
        int n = w * 256 + tid;
        float sc = xb[n * ROW + 4 + c];
        key[n] = ((u64)__float_as_uint(sc) << 32) | (u64)(2047 - n);
    }
    if (tid == 0) { s_kept = 0; s_done = 0; }
    __syncthreads();
    sort2048(key, tid, lane, wv);

    // stage all boxes in sorted order (336B row stride is 16B-aligned)
    #pragma unroll
    for (int w = 0; w < 8; w++) {
        int n = w * 256 + tid;
        u32 orig = 2047u - (u32)(key[n] & 0x7FFu);
        sbox[n] = *(const float4*)(xb + (size_t)orig * ROW);
    }
    __syncthreads();

    // ---- pipelined greedy: wave 0 scans chunk ch while waves 1-3 pre-test
    //      chunk ch+1 vs published kept; delta-test after B1 ----
    u64 mykey = key[lane];
    float4 bx = sbox[lane];
    float ar = __fmul_rn(__fsub_rn(bx.z, bx.x), __fsub_rn(bx.w, bx.y));
    u64 A = __ballot(__uint_as_float((u32)(mykey >> 32)) > SCORE_T);
    int keptc = 0;

    for (int ch = 0; ch < 32; ch++) {
        const int k0 = keptc;
        const bool have_next = (ch + 1 < 32);
        u64 nkey = 0;
        float4 nbx = make_float4(0.f, 0.f, 0.f, 0.f);
        float nar = 0.f;
        bool sup = false;

        if (wv == 0) {
            // serial accept/suppress scan of chunk ch (no barriers inside)
            u64 alive = A;
            int kept = k0;
            int done = 0;
            while (alive) {
                int bsel = (int)__builtin_ctzll(alive);
                if (lane == bsel) {
                    kept_box[kept] = bx;
                    kept_slot[kept] = (u16)(ch * 64 + bsel);
                }
                kept++;
                if (kept >= OUT_K) { done = 1; break; }
                alive &= alive - 1;
                if (!alive) break;
                float4 pb = make_float4(bcast(bx.x, bsel), bcast(bx.y, bsel),
                                        bcast(bx.z, bsel), bcast(bx.w, bsel));
                float pa = bcast(ar, bsel);
                alive &= ~__ballot(iou_gt_half(bx, ar, pb, pa));
            }
            if (lane == 0) { s_kept = kept; if (done) s_done = 1; }
            if (have_next) {
                nkey = key[(ch + 1) * 64 + lane];
                nbx = sbox[(ch + 1) * 64 + lane];
                nar = __fmul_rn(__fsub_rn(nbx.z, nbx.x), __fsub_rn(nbx.w, nbx.y));
            }
        } else if (have_next) {
            // pre-test chunk ch+1 vs kept[0..k0), split 3 ways (residue wv-1 mod 3)
            nkey = key[(ch + 1) * 64 + lane];
            nbx = sbox[(ch + 1) * 64 + lane];
            nar = __fmul_rn(__fsub_rn(nbx.z, nbx.x), __fsub_rn(nbx.w, nbx.y));
            sup = kept_test(kept_box, wv - 1, k0, 3, nbx, nar);
        }
        __syncthreads();                       // B1: kept list k1 published
        const int k1 = s_kept;
        if (s_done) break;                     // uniform: read post-barrier
        // delta-test chunk ch+1 vs kept[k0..k1), split 4 ways
        if (have_next && k1 > k0)
            sup = sup | kept_test(kept_box, k0 + wv, k1, 4, nbx, nar);
        bool nvalid = have_next &&
                      (__uint_as_float((u32)(nkey >> 32)) > SCORE_T);
        u64 nvb = __ballot(nvalid);
        u64 supb = __ballot(sup);
        if (lane == 0) s_sup[wv] = supb;
        __syncthreads();                       // B2: sup masks combined
        keptc = k1;
        if (nvb == 0) break;                   // sorted: nothing valid beyond
        A = nvb & ~(s_sup[0] | s_sup[1] | s_sup[2] | s_sup[3]);
        mykey = nkey; bx = nbx; ar = nar;
    }
    __syncthreads();
    const int kept_final = s_kept;

    // emit 200 keys; low32 packs ((0x3FFF - (c*200+slot)) << 11) | orig_idx
    // -> cross-class order (score desc, flat asc) matches reference top_k
    const int base_o = bc * OUT_K;
    if (tid < OUT_K) {
        u64 ok = 0ULL;
        if (tid < kept_final) {
            u64 kk = key[kept_slot[tid]];
            u32 flat = (u32)(c * OUT_K + tid);
            u32 orig = 2047u - (u32)(kk & 0x7FFu);
            ok = (kk & 0xFFFFFFFF00000000ULL) |
                 ((u64)(0x3FFFu - flat) << 11) | (u64)orig;
        }
        cand_key[base_o + tid] = ok;
    }

    // ---- fused finish: 8th finisher per class-group merges 8 runs;
    //      10th group-finisher per batch merges 10 runs and decodes ----
    __threadfence();                      // release cand_key
    if (tid == 0) {
        int old = atomicAdd(&cnt_g[b * NG + (c >> 3)], 1);
        s_role = (old == 7) ? 1 : 0;
    }
    __syncthreads();
    if (s_role == 1) {
        __threadfence();                  // acquire group's cand_key
        const int g = c >> 3;
        const u64* src = cand_key + (size_t)(b * NC + g * 8) * OUT_K;
        for (int i = tid; i < 2048; i += 256) {
            int run = i >> 8, pos = i & 255;
            buf[i] = (pos < OUT_K) ? src[run * OUT_K + pos] : 0ULL;
        }
        __syncthreads();
        pair_merge256(buf, wv * 512, 256, lane);
        __syncthreads();
        if (wv < 2) pair_merge256(buf, wv * 1024, 512, lane);
        __syncthreads();
        if (wv == 0) pair_merge256(buf, 0, 1024, lane);
        __syncthreads();
        ws2[(size_t)b * 2560 + g * 256 + tid] = buf[tid];
        __threadfence();                  // release ws2
        if (tid == 0) {
            int old2 = atomicAdd(&cnt_b[b], 1);
            s_role = (old2 == NG - 1) ? 2 : 0;
        }
        __syncthreads();
        if (s_role == 2) {
            __threadfence();              // acquire batch's ws2
            for (int i = tid; i < 4096; i += 256)
                buf[i] = (i < 2560) ? ws2[(size_t)b * 2560 + i] : 0ULL;
            __syncthreads();
            pair_merge256(buf, wv * 512, 256, lane);
            pair_merge256(buf, (wv + 4) * 512, 256, lane);
            __syncthreads();
            pair_merge256(buf, wv * 1024, 512, lane);
            __syncthreads();
            if (wv < 2) pair_merge256(buf, wv * 2048, 1024, lane);
            __syncthreads();
            if (wv == 0) pair_merge256(buf, 0, 2048, lane);
            __syncthreads();
            if (tid < OUT_K) {
                u64 kk = buf[tid];
                float* o = out + ((size_t)b * OUT_K + tid) * 6;
                if (kk == 0ULL) {
                    o[0] = 0.f; o[1] = 0.f; o[2] = 0.f;
                    o[3] = 0.f; o[4] = 0.f; o[5] = 0.f;
                } else {
                    u32 lo = (u32)(kk & 0xFFFFFFFFu);
                    u32 flat = 0x3FFFu - ((lo >> 11) & 0x3FFFu);
                    int cls = flat / OUT_K;
                    u32 n = lo & 0x7FFu;
                    float scf = __uint_as_float((u32)(kk >> 32));
                    float4 bb = *(const float4*)(xb + (size_t)n * ROW);
                    o[0] = (float)cls;
                    o[1] = scf;
                    o[2] = fminf(fmaxf(bb.x, 0.0f), 1.0f);
                    o[3] = fminf(fmaxf(bb.y, 0.0f), 1.0f);
                    o[4] = fminf(fmaxf(bb.z, 0.0f), 1.0f);
                    o[5] = fminf(fmaxf(bb.w, 0.0f), 1.0f);
                }
            }
        }
    }
}

extern "C" void kernel_launch(void* const* d_in, const int* in_sizes, int n_in,
                              void* d_out, int out_size, void* d_ws, size_t ws_size,
                              hipStream_t stream) {
    const float* x = (const float*)d_in[0];
    float* out = (float*)d_out;
    // ws: cand_key 8*80*200*8 = 1,024,000 B
    //     ws2      8*2560*8   =   163,840 B
    //     counters (80+8)*4   =       352 B
    u64* cand_key = (u64*)d_ws;
    u64* ws2 = (u64*)((char*)d_ws + 1024000);
    int* cnt_g = (int*)((char*)d_ws + 1024000 + 163840);
    int* cnt_b = cnt_g + NB * NG;
    hipMemsetAsync((void*)cnt_g, 0, (NB * NG + NB) * sizeof(int), stream);
    nms_fused<<<NB * NC, 256, 0, stream>>>(x, cand_key, ws2, cnt_g, cnt_b, out);
}